// Round 1
// baseline (263.948 us; speedup 1.0000x reference)
//
#include <hip/hip_runtime.h>

// g2[b,c,h,w] = sum_d cost[b,d,h,w] * h1[b,c,h,w+d]   (w+d < W, else 0)
// B=4 C=32 H=256 W=512 D=48, fp32 in/out.
//
// Block = one (b, h, w-half). Stages h1[b, :, h, wstart .. wstart+311] into
// LDS (zero-padded past W). Thread = 2 channels x 8 w, slides a 12-float h1
// window in registers across the d loop (3-quad circular buffer, period-3
// static rotation so indices constant-fold). Cost read straight from global
// (L1/L2 absorb the x16 intra-block reuse; HBM traffic stays compulsory).

#define BB 4
#define CC 32
#define HH 256
#define WW 512
#define DDISP 48
#define HW (HH * WW)        // 131072
#define TW 256              // w-range per block
#define WPAD 316            // 308 needed (TW + 44 + 15); 316 = 4 mod 8 words -> bank spread
#define NT 512

__global__ __launch_bounds__(NT, 2)
void dense_warp_kernel(const float* __restrict__ h1,
                       const float* __restrict__ cost,
                       float* __restrict__ out)
{
    __shared__ float h1s[CC * WPAD];   // 40448 B

    const int blk    = blockIdx.x;
    const int wside  = blk & 1;
    const int h      = (blk >> 1) & (HH - 1);
    const int b      = blk >> 9;
    const int wstart = wside * TW;
    const int tid    = threadIdx.x;

    // ---- stage h1[b, :, h, wstart .. wstart+311] into LDS (zeros past W) ----
    {
        const float* src = h1 + ((size_t)b * CC * HH + (size_t)h) * WW;  // + r*HW + w
        for (int idx = tid; idx < CC * 78; idx += NT) {   // 78 quads = 312 floats/row
            int r    = idx / 78;
            int q    = idx - r * 78;
            int col  = q << 2;
            int wsrc = wstart + col;
            float4 v = make_float4(0.f, 0.f, 0.f, 0.f);
            if (wsrc < WW) v = *(const float4*)(src + (size_t)r * HW + wsrc);
            *(float4*)(&h1s[r * WPAD + col]) = v;
        }
    }
    __syncthreads();

    const int wg = tid & 31;          // 32 w-groups of 8
    const int cg = tid >> 5;          // 16 channel-groups of 2
    const int w0 = wg << 3;           // local w offset, 0..248
    const int c0 = cg << 1;

    float acc[2][8];
#pragma unroll
    for (int c = 0; c < 2; ++c)
#pragma unroll
        for (int j = 0; j < 8; ++j) acc[c][j] = 0.f;

    // window invariant at start of group g: quad[(g+k)%3] = h1[w0 + 4g + 4k], k=0..2
    float win[2][12];
#pragma unroll
    for (int c = 0; c < 2; ++c) {
        const float* p = &h1s[(c0 + c) * WPAD + w0];
#pragma unroll
        for (int q = 0; q < 3; ++q) {
            float4 v = *(const float4*)(p + (q << 2));
            win[c][q * 4 + 0] = v.x; win[c][q * 4 + 1] = v.y;
            win[c][q * 4 + 2] = v.z; win[c][q * 4 + 3] = v.w;
        }
    }

    const float* costBase = cost + ((size_t)b * DDISP * HH + (size_t)h) * WW + wstart + w0;

#define GROUP(G, gexpr) do {                                                   \
    const int g_ = (gexpr);                                                    \
    _Pragma("unroll")                                                          \
    for (int dd = 0; dd < 4; ++dd) {                                           \
        const float* cp = costBase + (size_t)(4 * g_ + dd) * HW;               \
        float4 ca = *(const float4*)cp;                                        \
        float4 cbv = *(const float4*)(cp + 4);                                 \
        float c8[8] = {ca.x, ca.y, ca.z, ca.w, cbv.x, cbv.y, cbv.z, cbv.w};    \
        _Pragma("unroll")                                                      \
        for (int c = 0; c < 2; ++c) {                                          \
            _Pragma("unroll")                                                  \
            for (int j = 0; j < 8; ++j) {                                      \
                const int o = dd + j;              /* 0..10 */                 \
                const int s = ((G) + (o >> 2)) % 3;                            \
                acc[c][j] += c8[j] * win[c][s * 4 + (o & 3)];                   \
            }                                                                  \
        }                                                                      \
    }                                                                          \
    _Pragma("unroll")                                                          \
    for (int c = 0; c < 2; ++c) {  /* slide: oldest quad <- h1[w0+4g+12..15] */ \
        float4 v = *(const float4*)(&h1s[(c0 + c) * WPAD + w0 + 4 * g_ + 12]); \
        win[c][(G) * 4 + 0] = v.x; win[c][(G) * 4 + 1] = v.y;                  \
        win[c][(G) * 4 + 2] = v.z; win[c][(G) * 4 + 3] = v.w;                  \
    }                                                                          \
} while (0)

    for (int g3 = 0; g3 < 4; ++g3) {   // 12 groups of 4 disparities = 48
        GROUP(0, g3 * 3 + 0);
        GROUP(1, g3 * 3 + 1);
        GROUP(2, g3 * 3 + 2);
    }
#undef GROUP

    float* outBase = out + ((size_t)b * CC * HH + (size_t)h) * WW + wstart + w0;
#pragma unroll
    for (int c = 0; c < 2; ++c) {
        float* op = outBase + (size_t)(c0 + c) * HW;
        *(float4*)op       = make_float4(acc[c][0], acc[c][1], acc[c][2], acc[c][3]);
        *(float4*)(op + 4) = make_float4(acc[c][4], acc[c][5], acc[c][6], acc[c][7]);
    }
}

extern "C" void kernel_launch(void* const* d_in, const int* in_sizes, int n_in,
                              void* d_out, int out_size, void* d_ws, size_t ws_size,
                              hipStream_t stream) {
    const float* h1   = (const float*)d_in[0];
    const float* cost = (const float*)d_in[1];
    float* out        = (float*)d_out;
    dim3 grid(BB * HH * 2);   // 2048 blocks: (b, h, w-half)
    dense_warp_kernel<<<grid, NT, 0, stream>>>(h1, cost, out);
}

// Round 2
// 247.815 us; speedup vs baseline: 1.0651x; 1.0651x over previous
//
#include <hip/hip_runtime.h>

// g2[b,c,h,w] = sum_d cost[b,d,h,w] * h1[b,c,h,w+d]   (w+d < W, else 0)
// B=4 C=32 H=256 W=512 D=48, fp32.
//
// Block = (b, h, w-half): stages h1[b, :, h, wstart..wstart+311] into LDS
// (zero past W). NT=256 = 4 waves; wave = 8-channel group; lane owns 4
// consecutive w (w0 = lane*4) -> every ds_read_b128 is 16B/lane contiguous
// across the wave = conflict-free. Per channel a 2-quad (8-float) register
// window slides by one quad per 4-disparity group (period-2 rotation,
// statically unrolled). Cost dwordx4 serves 32 FMAs (8 channels).

#define BB 4
#define CC 32
#define HH 256
#define WW 512
#define DDISP 48
#define HW (HH * WW)     // 131072
#define TW 256
#define WROW 312         // 308 needed (TW + 47 + 4, quad-rounded) + 4 pad
#define NT 256

__global__ __launch_bounds__(NT, 4)
void dense_warp_kernel(const float* __restrict__ h1,
                       const float* __restrict__ cost,
                       float* __restrict__ out)
{
    __shared__ float h1s[CC * WROW];   // 39936 B -> 4 blocks/CU

    const int blk    = blockIdx.x;
    const int wside  = blk & 1;
    const int h      = (blk >> 1) & (HH - 1);
    const int b      = blk >> 9;
    const int wstart = wside * TW;
    const int tid    = threadIdx.x;

    // ---- stage h1[b, :, h, wstart .. wstart+311] into LDS (zeros past W) ----
    {
        const float* src = h1 + ((size_t)b * CC * HH + (size_t)h) * WW;
        for (int idx = tid; idx < CC * 78; idx += NT) {   // 78 quads/row
            int r    = idx / 78;
            int q    = idx - r * 78;
            int col  = q << 2;
            int wsrc = wstart + col;
            float4 v = make_float4(0.f, 0.f, 0.f, 0.f);
            if (wsrc < WW) v = *(const float4*)(src + (size_t)r * HW + wsrc);
            *(float4*)(&h1s[r * WROW + col]) = v;
        }
    }
    __syncthreads();

    const int lane = tid & 63;
    const int wid  = tid >> 6;        // 0..3 -> channel group
    const int c0   = wid << 3;        // 8 channels per thread
    const int w0   = lane << 2;       // 4 consecutive w per lane

    float acc[8][4];
#pragma unroll
    for (int c = 0; c < 8; ++c)
#pragma unroll
        for (int j = 0; j < 4; ++j) acc[c][j] = 0.f;

    // win[c][slot*4+k]: slot holds quad (g + slot_phase); invariant at start of
    // group g: circular slot (g&1) = h1 quad at w0+4g, slot ((g+1)&1) = w0+4g+4.
    float win[8][8];
    const float* lptr = &h1s[c0 * WROW + w0];   // advances by 4 floats per group
#pragma unroll
    for (int c = 0; c < 8; ++c) {
        float4 q0 = *(const float4*)(lptr + c * WROW);
        float4 q1 = *(const float4*)(lptr + c * WROW + 4);
        win[c][0] = q0.x; win[c][1] = q0.y; win[c][2] = q0.z; win[c][3] = q0.w;
        win[c][4] = q1.x; win[c][5] = q1.y; win[c][6] = q1.z; win[c][7] = q1.w;
    }

    const float* cp = cost + ((size_t)b * DDISP * HH + (size_t)h) * WW + wstart + w0;

    float cv[4][4];

#define LOADC(gofs) do {                                                       \
    _Pragma("unroll")                                                          \
    for (int dd = 0; dd < 4; ++dd) {                                           \
        float4 t = *(const float4*)(cp + (size_t)((gofs) + dd) * HW);          \
        cv[dd][0] = t.x; cv[dd][1] = t.y; cv[dd][2] = t.z; cv[dd][3] = t.w;    \
    }                                                                          \
} while (0)

#define DO_GROUP(P) do {                                                       \
    _Pragma("unroll")                                                          \
    for (int c = 0; c < 8; ++c) {                                              \
        _Pragma("unroll")                                                      \
        for (int dd = 0; dd < 4; ++dd) {                                       \
            _Pragma("unroll")                                                  \
            for (int j = 0; j < 4; ++j) {                                      \
                const int o    = dd + j;                /* 0..6 */             \
                const int slot = ((P) + (o >> 2)) & 1;                         \
                acc[c][j] += cv[dd][j] * win[c][slot * 4 + (o & 3)];           \
            }                                                                  \
        }                                                                      \
        /* slide: replace oldest quad (slot P) with quad g+2 */                \
        float4 t = *(const float4*)(lptr + c * WROW + 8);                      \
        win[c][(P) * 4 + 0] = t.x; win[c][(P) * 4 + 1] = t.y;                  \
        win[c][(P) * 4 + 2] = t.z; win[c][(P) * 4 + 3] = t.w;                  \
    }                                                                          \
    lptr += 4;                                                                 \
} while (0)

    // 12 groups of 4 disparities; group g covers d = 4g..4g+3
    for (int ig = 0; ig < 6; ++ig) {
        LOADC(0);          // d rows 8*ig .. +3
        DO_GROUP(0);
        LOADC(4);          // d rows 8*ig+4 .. +7
        DO_GROUP(1);
        cp += (size_t)8 * HW;
    }
#undef LOADC
#undef DO_GROUP

    float* outBase = out + ((size_t)b * CC * HH + (size_t)h) * WW + wstart + w0;
#pragma unroll
    for (int c = 0; c < 8; ++c) {
        float* op = outBase + (size_t)(c0 + c) * HW;
        *(float4*)op = make_float4(acc[c][0], acc[c][1], acc[c][2], acc[c][3]);
    }
}

extern "C" void kernel_launch(void* const* d_in, const int* in_sizes, int n_in,
                              void* d_out, int out_size, void* d_ws, size_t ws_size,
                              hipStream_t stream) {
    const float* h1   = (const float*)d_in[0];
    const float* cost = (const float*)d_in[1];
    float* out        = (float*)d_out;
    dim3 grid(BB * HH * 2);   // (b, h, w-half)
    dense_warp_kernel<<<grid, NT, 0, stream>>>(h1, cost, out);
}